// Round 1
// baseline (239.035 us; speedup 1.0000x reference)
//
#include <hip/hip_runtime.h>
#include <math.h>

// EqualtimeLayer: for each (b, post): sort 1024 events by t = spike[b][pre] +
// delay[pre][post], prefix-sum w and w*t in sorted order, candidate crossing
// tmp_k = (theta + cumwt_k)/cumw_k valid iff cumw_k>0 && tmp>=t_k &&
// (k==last || tmp<=t_{k+1}); output = min valid tmp.
//
// Strategy: counting sort by value-bucket (1024 buckets over [0,2)) + exact
// within-bucket rank fixup, all in LDS. One workgroup handles one post column
// (delays/weights column cached in registers) for 16 batches.

#define B_TOT 32
#define PRE 1024
#define POST 1024
#define NBUCK 1024
#define TPB 256
#define EPT 4          // elements per thread (TPB*EPT == PRE)
#define B_PER_WG 16    // batches per workgroup

__global__ __launch_bounds__(TPB, 4) void equaltime_kernel(
    const float* __restrict__ spikes,     // [B][PRE]
    const float* __restrict__ weights,    // [PRE][POST]
    const float* __restrict__ delays,     // [PRE][POST]
    const float* __restrict__ thresholds, // [POST]
    float* __restrict__ out)              // [B][POST]
{
    __shared__ float s_t[PRE];     // sorted event times
    __shared__ float s_w[PRE];     // sorted event weights
    __shared__ int   s_cnt[NBUCK]; // bucket counts (preserved)
    __shared__ int   s_off[NBUCK]; // bucket exclusive offsets
    __shared__ int   s_isum[4];    // per-wave int scan partials
    __shared__ float s_fw[4], s_fwt[4]; // per-wave float scan partials
    __shared__ float s_red[4];     // per-wave min partials

    const int tid  = threadIdx.x;
    const int lane = tid & 63;
    const int wid  = tid >> 6;
    const int bx   = blockIdx.x;
    const int post = bx >> 1;            // 2 WGs per post
    const int b0   = (bx & 1) * B_PER_WG;
    const float theta = thresholds[post];

    // Cache this post's delay/weight column slice in registers.
    // (Column access: stride 4KB, uncoalesced, but done once per WG and
    //  amortized over B_PER_WG iterations; L2/LLC absorbs reuse across WGs.)
    float dly[EPT], wgt[EPT];
#pragma unroll
    for (int j = 0; j < EPT; ++j) {
        int pre = tid * EPT + j;
        dly[j] = delays[pre * POST + post];
        wgt[j] = weights[pre * POST + post];
    }

    for (int bi = 0; bi < B_PER_WG; ++bi) {
        const int b = b0 + bi;
        __syncthreads(); // protect LDS reuse from previous iteration

        // ---- zero bucket counts ----
#pragma unroll
        for (int j = 0; j < EPT; ++j) s_cnt[tid * EPT + j] = 0;
        __syncthreads();

        // ---- event times, bucket index, arrival rank ----
        float4 sp = *reinterpret_cast<const float4*>(spikes + b * PRE + tid * EPT);
        float tv[EPT] = {sp.x + dly[0], sp.y + dly[1], sp.z + dly[2], sp.w + dly[3]};
        int bkt[EPT], rnk[EPT];
#pragma unroll
        for (int j = 0; j < EPT; ++j) {
            int k = (int)(tv[j] * 512.0f);        // bucket width 1/512 over [0,2)
            k = k < 0 ? 0 : (k > NBUCK - 1 ? NBUCK - 1 : k);
            bkt[j] = k;
            rnk[j] = atomicAdd(&s_cnt[k], 1);
        }
        __syncthreads();

        // ---- exclusive scan of counts -> s_off ----
        int c[EPT], ls[EPT];
        int s = 0;
#pragma unroll
        for (int j = 0; j < EPT; ++j) { c[j] = s_cnt[tid * EPT + j]; s += c[j]; ls[j] = s; }
        int x = s;
#pragma unroll
        for (int off = 1; off < 64; off <<= 1) {
            int y = __shfl_up(x, off);
            if (lane >= off) x += y;
        }
        if (lane == 63) s_isum[wid] = x;
        __syncthreads();
        int wbase = 0;
        for (int k2 = 0; k2 < wid; ++k2) wbase += s_isum[k2];
        int base = wbase + x - s; // exclusive prefix of this thread's first bucket
#pragma unroll
        for (int j = 0; j < EPT; ++j) s_off[tid * EPT + j] = base + ls[j] - c[j];
        __syncthreads();

        // ---- scatter (arrival order within bucket) ----
        int pos[EPT];
#pragma unroll
        for (int j = 0; j < EPT; ++j) {
            pos[j] = s_off[bkt[j]] + rnk[j];
            s_t[pos[j]] = tv[j];
            s_w[pos[j]] = wgt[j];
        }
        __syncthreads();

        // ---- exact-rank fixup within multi-element buckets ----
        int npos[EPT];
#pragma unroll
        for (int j = 0; j < EPT; ++j) {
            npos[j] = -1;
            int cnt = s_cnt[bkt[j]];
            if (cnt > 1) {
                int bas = s_off[bkt[j]];
                int r = 0;
                for (int k2 = bas; k2 < bas + cnt; ++k2) {
                    float tk = s_t[k2];
                    r += (tk < tv[j]) || (tk == tv[j] && k2 < pos[j]);
                }
                npos[j] = bas + r;
            }
        }
        __syncthreads();
#pragma unroll
        for (int j = 0; j < EPT; ++j) {
            if (npos[j] >= 0) { s_t[npos[j]] = tv[j]; s_w[npos[j]] = wgt[j]; }
        }
        __syncthreads();

        // ---- inclusive scan of (w, w*t) over sorted order ----
        float st[EPT], sw[EPT], cw[EPT], cwt[EPT];
#pragma unroll
        for (int j = 0; j < EPT; ++j) { st[j] = s_t[tid * EPT + j]; sw[j] = s_w[tid * EPT + j]; }
        float aw = 0.f, awt = 0.f;
#pragma unroll
        for (int j = 0; j < EPT; ++j) { aw += sw[j]; awt += sw[j] * st[j]; cw[j] = aw; cwt[j] = awt; }
        float xw = aw, xwt = awt;
#pragma unroll
        for (int off = 1; off < 64; off <<= 1) {
            float yw  = __shfl_up(xw, off);
            float ywt = __shfl_up(xwt, off);
            if (lane >= off) { xw += yw; xwt += ywt; }
        }
        if (lane == 63) { s_fw[wid] = xw; s_fwt[wid] = xwt; }
        __syncthreads();
        float bw = 0.f, bwt = 0.f;
        for (int k2 = 0; k2 < wid; ++k2) { bw += s_fw[k2]; bwt += s_fwt[k2]; }
        bw += xw - aw; bwt += xwt - awt; // exclusive prefix for this thread

        // ---- candidates + min ----
        float tnext = (tid < TPB - 1) ? s_t[tid * EPT + EPT] : 0.f;
        float m = INFINITY;
#pragma unroll
        for (int j = 0; j < EPT; ++j) {
            float W  = bw + cw[j];
            float WT = bwt + cwt[j];
            if (W > 0.f) {
                float tmp = (theta + WT) / W;
                bool ok = (tmp >= st[j]);          // !(tmp < t_k)
                int i = tid * EPT + j;
                if (i < PRE - 1) {
                    float tn = (j < EPT - 1) ? st[j + 1] : tnext;
                    ok = ok && (tmp <= tn);        // !(tmp > t_{k+1})
                }
                if (ok) m = fminf(m, tmp);
            }
        }
#pragma unroll
        for (int off = 32; off >= 1; off >>= 1) m = fminf(m, __shfl_down(m, off));
        if (lane == 0) s_red[wid] = m;
        __syncthreads();
        if (tid == 0) {
            out[b * POST + post] =
                fminf(fminf(s_red[0], s_red[1]), fminf(s_red[2], s_red[3]));
        }
    }
}

extern "C" void kernel_launch(void* const* d_in, const int* in_sizes, int n_in,
                              void* d_out, int out_size, void* d_ws, size_t ws_size,
                              hipStream_t stream) {
    const float* spikes     = (const float*)d_in[0]; // [32,1024]
    const float* weights    = (const float*)d_in[1]; // [1024,1024]
    const float* delays     = (const float*)d_in[2]; // [1024,1024]
    const float* thresholds = (const float*)d_in[3]; // [1024]
    float* outp = (float*)d_out;                     // [32,1024]

    dim3 grid(POST * (B_TOT / B_PER_WG)); // 2048 workgroups
    dim3 block(TPB);
    equaltime_kernel<<<grid, block, 0, stream>>>(spikes, weights, delays, thresholds, outp);
}

// Round 2
// 215.287 us; speedup vs baseline: 1.1103x; 1.1103x over previous
//
#include <hip/hip_runtime.h>
#include <math.h>

// EqualtimeLayer: for each (b, post): sort 1024 events by t = spike[b][pre] +
// delay[pre][post], prefix-sum (w, w*t) in sorted order, candidate crossing
// tmp_k = (theta + cumwt_k)/cumw_k valid iff cumw_k>0 && tmp>=t_k &&
// (k==last || tmp<=t_{k+1}); output = min valid tmp.
//
// Counting sort by value bucket (1024 buckets over [0,2)) + exact in-bucket
// rank fixup, all in LDS. One WG per (post, 16 batches).
// R2: float2-interleaved sorted array (ds_read_b128/ds_write_b64, kills the
// 8-way strided bank conflicts), int4 count ops, packed (off<<12|cnt) single
// array, barrier moved, XCD-contiguous block swizzle.

#define B_TOT 32
#define PRE 1024
#define POST 1024
#define NBUCK 1024
#define TPB 256
#define EPT 4          // elements per thread (TPB*EPT == PRE)
#define B_PER_WG 16    // batches per workgroup

__global__ __launch_bounds__(TPB, 8) void equaltime_kernel(
    const float* __restrict__ spikes,     // [B][PRE]
    const float* __restrict__ weights,    // [PRE][POST]
    const float* __restrict__ delays,     // [PRE][POST]
    const float* __restrict__ thresholds, // [POST]
    float* __restrict__ out)              // [B][POST]
{
    __shared__ __align__(16) float2 s_tw[PRE];  // sorted (t, w) pairs, 8 KB
    __shared__ __align__(16) int    s_cnt[NBUCK]; // counts, then packed off<<12|cnt
    __shared__ int   s_isum[4];
    __shared__ float s_fw[4], s_fwt[4];
    __shared__ float s_red[4];

    const int tid  = threadIdx.x;
    const int lane = tid & 63;
    const int wid  = tid >> 6;

    // XCD-contiguous swizzle: HW round-robins blockIdx%8 across XCDs; remap so
    // each XCD covers a contiguous range of posts (weight/delay cache-line
    // reuse across the 16 posts sharing a 64B line stays in one XCD's L2).
    const int bx   = blockIdx.x;
    const int sbx  = (bx & 7) * 256 + (bx >> 3);
    const int post = sbx >> 1;            // 2 WGs per post
    const int b0   = (sbx & 1) * B_PER_WG;
    const float theta = thresholds[post];

    // Cache this post's delay/weight column slice in registers (uncoalesced
    // column loads, done once per WG, amortized over B_PER_WG batches).
    float dly[EPT], wgt[EPT];
#pragma unroll
    for (int j = 0; j < EPT; ++j) {
        int pre = tid * EPT + j;
        dly[j] = delays[pre * POST + post];
        wgt[j] = weights[pre * POST + post];
    }

    // zero counts for the first iteration
    reinterpret_cast<int4*>(s_cnt)[tid] = make_int4(0, 0, 0, 0);
    __syncthreads();

    for (int bi = 0; bi < B_PER_WG; ++bi) {
        const int b = b0 + bi;

        // ---- event times, bucket index, arrival rank (LDS atomics) ----
        float4 sp = *reinterpret_cast<const float4*>(spikes + b * PRE + tid * EPT);
        float tv[EPT] = {sp.x + dly[0], sp.y + dly[1], sp.z + dly[2], sp.w + dly[3]};
        int bkt[EPT], rnk[EPT];
#pragma unroll
        for (int j = 0; j < EPT; ++j) {
            int k = (int)(tv[j] * 512.0f);        // bucket width 1/512 over [0,2)
            k = k < 0 ? 0 : (k > NBUCK - 1 ? NBUCK - 1 : k);
            bkt[j] = k;
            rnk[j] = atomicAdd(&s_cnt[k], 1);
        }
        __syncthreads();                                        // B1

        // ---- exclusive scan of counts -> packed (off<<12 | cnt) ----
        int4 cv = reinterpret_cast<int4*>(s_cnt)[tid];
        int c[EPT] = {cv.x, cv.y, cv.z, cv.w};
        int ls[EPT];
        int s = 0;
#pragma unroll
        for (int j = 0; j < EPT; ++j) { s += c[j]; ls[j] = s; }
        int x = s;
#pragma unroll
        for (int off = 1; off < 64; off <<= 1) {
            int y = __shfl_up(x, off);
            if (lane >= off) x += y;
        }
        if (lane == 63) s_isum[wid] = x;
        __syncthreads();                                        // B2
        int wbase = 0;
        for (int k2 = 0; k2 < wid; ++k2) wbase += s_isum[k2];
        int base = wbase + x - s; // exclusive prefix of this thread's first bucket
        int4 pv;
        pv.x = ((base + ls[0] - c[0]) << 12) | c[0];
        pv.y = ((base + ls[1] - c[1]) << 12) | c[1];
        pv.z = ((base + ls[2] - c[2]) << 12) | c[2];
        pv.w = ((base + ls[3] - c[3]) << 12) | c[3];
        reinterpret_cast<int4*>(s_cnt)[tid] = pv;
        __syncthreads();                                        // B3

        // ---- scatter (arrival order within bucket) ----
        int pc[EPT], pos[EPT];
#pragma unroll
        for (int j = 0; j < EPT; ++j) {
            pc[j]  = s_cnt[bkt[j]];
            pos[j] = (pc[j] >> 12) + rnk[j];
            s_tw[pos[j]] = make_float2(tv[j], wgt[j]);
        }
        __syncthreads();                                        // B4

        // ---- exact-rank fixup within multi-element buckets ----
        int npos[EPT];
#pragma unroll
        for (int j = 0; j < EPT; ++j) {
            npos[j] = -1;
            int cnt = pc[j] & 0xFFF;
            if (cnt > 1) {
                int bas = pc[j] >> 12;
                int r = 0;
                for (int k2 = bas; k2 < bas + cnt; ++k2) {
                    float tk = s_tw[k2].x;
                    r += (tk < tv[j]) || (tk == tv[j] && k2 < pos[j]);
                }
                npos[j] = bas + r;
            }
        }
        __syncthreads();                                        // B5
        // s_cnt is dead now: zero it for the next iteration (overlaps rewrite)
        reinterpret_cast<int4*>(s_cnt)[tid] = make_int4(0, 0, 0, 0);
#pragma unroll
        for (int j = 0; j < EPT; ++j) {
            if (npos[j] >= 0) s_tw[npos[j]] = make_float2(tv[j], wgt[j]);
        }
        __syncthreads();                                        // B6

        // ---- inclusive scan of (w, w*t) over sorted order ----
        float4 q0 = reinterpret_cast<const float4*>(s_tw)[tid * 2];
        float4 q1 = reinterpret_cast<const float4*>(s_tw)[tid * 2 + 1];
        float st[EPT] = {q0.x, q0.z, q1.x, q1.z};
        float sw[EPT] = {q0.y, q0.w, q1.y, q1.w};
        float cw[EPT], cwt[EPT];
        float aw = 0.f, awt = 0.f;
#pragma unroll
        for (int j = 0; j < EPT; ++j) { aw += sw[j]; awt += sw[j] * st[j]; cw[j] = aw; cwt[j] = awt; }
        float xw = aw, xwt = awt;
#pragma unroll
        for (int off = 1; off < 64; off <<= 1) {
            float yw  = __shfl_up(xw, off);
            float ywt = __shfl_up(xwt, off);
            if (lane >= off) { xw += yw; xwt += ywt; }
        }
        if (lane == 63) { s_fw[wid] = xw; s_fwt[wid] = xwt; }
        float tnext = (tid < TPB - 1) ? s_tw[tid * EPT + EPT].x : 0.f;
        __syncthreads();                                        // B7
        float bw = 0.f, bwt = 0.f;
        for (int k2 = 0; k2 < wid; ++k2) { bw += s_fw[k2]; bwt += s_fwt[k2]; }
        bw += xw - aw; bwt += xwt - awt; // exclusive prefix for this thread

        // ---- candidates + min ----
        float m = INFINITY;
#pragma unroll
        for (int j = 0; j < EPT; ++j) {
            float W  = bw + cw[j];
            float WT = bwt + cwt[j];
            if (W > 0.f) {
                float tmp = (theta + WT) / W;
                bool ok = (tmp >= st[j]);          // !(tmp < t_k)
                int i = tid * EPT + j;
                if (i < PRE - 1) {
                    float tn = (j < EPT - 1) ? st[j + 1] : tnext;
                    ok = ok && (tmp <= tn);        // !(tmp > t_{k+1})
                }
                if (ok) m = fminf(m, tmp);
            }
        }
#pragma unroll
        for (int off = 32; off >= 1; off >>= 1) m = fminf(m, __shfl_down(m, off));
        if (lane == 0) s_red[wid] = m;
        __syncthreads();                                        // B8
        if (tid == 0) {
            out[b * POST + post] =
                fminf(fminf(s_red[0], s_red[1]), fminf(s_red[2], s_red[3]));
        }
    }
}

extern "C" void kernel_launch(void* const* d_in, const int* in_sizes, int n_in,
                              void* d_out, int out_size, void* d_ws, size_t ws_size,
                              hipStream_t stream) {
    const float* spikes     = (const float*)d_in[0]; // [32,1024]
    const float* weights    = (const float*)d_in[1]; // [1024,1024]
    const float* delays     = (const float*)d_in[2]; // [1024,1024]
    const float* thresholds = (const float*)d_in[3]; // [1024]
    float* outp = (float*)d_out;                     // [32,1024]

    dim3 grid(POST * (B_TOT / B_PER_WG)); // 2048 workgroups
    dim3 block(TPB);
    equaltime_kernel<<<grid, block, 0, stream>>>(spikes, weights, delays, thresholds, outp);
}

// Round 3
// 186.028 us; speedup vs baseline: 1.2849x; 1.1573x over previous
//
#include <hip/hip_runtime.h>
#include <math.h>

// EqualtimeLayer: for each (b, post): sort 1024 events by t = spike[b][pre] +
// delay[pre][post], prefix-sum (w, w*t) in sorted order, candidate crossing
// tmp_k = (theta + cumwt_k)/cumw_k valid iff cumw_k>0 && tmp>=t_k &&
// (k==last || tmp<=t_{k+1}); output = min valid tmp.
//
// Counting sort by value bucket (1024 buckets over [0,2)) + exact in-bucket
// rank fixup, all in LDS. One WG per (post, 8 batches).
// R3: DPP wave scans (no ds_bpermute), v_rcp division, 12 WG/CU occupancy.

#define B_TOT 32
#define PRE 1024
#define POST 1024
#define NBUCK 1024
#define TPB 256
#define EPT 4          // elements per thread (TPB*EPT == PRE)
#define B_PER_WG 8     // batches per workgroup -> 4096 WGs

// ---- DPP helpers (gfx9 encodings: row_shr:N=0x110|N, BCAST15=0x142, BCAST31=0x143,
//      row_mirror=0x140, half_mirror=0x141, quad_perm = 0x00..0xFF) ----
template<int CTRL, int MASK>
__device__ __forceinline__ int dpp_add_i32(int v) {
    return v + __builtin_amdgcn_update_dpp(0, v, CTRL, MASK, 0xf, true);
}
template<int CTRL, int MASK>
__device__ __forceinline__ float dpp_add_f32(float v) {
    int t = __builtin_amdgcn_update_dpp(0, __float_as_int(v), CTRL, MASK, 0xf, true);
    return v + __int_as_float(t);
}
template<int CTRL>
__device__ __forceinline__ float dpp_min_f32(float v) {
    int t = __builtin_amdgcn_update_dpp(__float_as_int(v), __float_as_int(v), CTRL, 0xf, 0xf, false);
    return fminf(v, __int_as_float(t));
}
// 64-lane inclusive scan: 4 row_shr steps + bcast15 (rows 1,3) + bcast31 (rows 2,3)
__device__ __forceinline__ int wave_iscan_i32(int v) {
    v = dpp_add_i32<0x111, 0xf>(v);
    v = dpp_add_i32<0x112, 0xf>(v);
    v = dpp_add_i32<0x114, 0xf>(v);
    v = dpp_add_i32<0x118, 0xf>(v);
    v = dpp_add_i32<0x142, 0xa>(v);
    v = dpp_add_i32<0x143, 0xc>(v);
    return v;
}
__device__ __forceinline__ float wave_iscan_f32(float v) {
    v = dpp_add_f32<0x111, 0xf>(v);
    v = dpp_add_f32<0x112, 0xf>(v);
    v = dpp_add_f32<0x114, 0xf>(v);
    v = dpp_add_f32<0x118, 0xf>(v);
    v = dpp_add_f32<0x142, 0xa>(v);
    v = dpp_add_f32<0x143, 0xc>(v);
    return v;
}

__global__ __launch_bounds__(TPB, 12) void equaltime_kernel(
    const float* __restrict__ spikes,     // [B][PRE]
    const float* __restrict__ weights,    // [PRE][POST]
    const float* __restrict__ delays,     // [PRE][POST]
    const float* __restrict__ thresholds, // [POST]
    float* __restrict__ out)              // [B][POST]
{
    __shared__ __align__(16) float2 s_tw[PRE];    // sorted (t, w) pairs, 8 KB
    __shared__ __align__(16) int    s_cnt[NBUCK]; // counts, then packed off<<12|cnt
    __shared__ int   s_isum[4];
    __shared__ float s_fw[4], s_fwt[4];
    __shared__ float s_red[4];

    const int tid  = threadIdx.x;
    const int lane = tid & 63;
    const int wid  = tid >> 6;

    // XCD-contiguous swizzle: HW round-robins blockIdx%8 across XCDs; remap so
    // each XCD owns a contiguous 128-post band (weight/delay cache-line reuse
    // across the 16 posts sharing a 64B line stays in one XCD's L2).
    const int bx   = blockIdx.x;
    const int sbx  = (bx & 7) * 512 + (bx >> 3);
    const int post = sbx >> 2;            // 4 WGs per post
    const int b0   = (sbx & 3) * B_PER_WG;
    const float theta = thresholds[post];

    // Cache this post's delay/weight column slice in registers (uncoalesced
    // column loads, done once per WG, amortized over B_PER_WG batches;
    // same-XCD L2 absorbs the 64 WGs sharing each line band).
    float dly[EPT], wgt[EPT];
#pragma unroll
    for (int j = 0; j < EPT; ++j) {
        int pre = tid * EPT + j;
        dly[j] = delays[pre * POST + post];
        wgt[j] = weights[pre * POST + post];
    }

    // zero counts for the first iteration
    reinterpret_cast<int4*>(s_cnt)[tid] = make_int4(0, 0, 0, 0);
    __syncthreads();

    for (int bi = 0; bi < B_PER_WG; ++bi) {
        const int b = b0 + bi;

        // ---- event times, bucket index, arrival rank (LDS atomics) ----
        float4 sp = *reinterpret_cast<const float4*>(spikes + b * PRE + tid * EPT);
        float tv[EPT] = {sp.x + dly[0], sp.y + dly[1], sp.z + dly[2], sp.w + dly[3]};
        int bkt[EPT], rnk[EPT];
#pragma unroll
        for (int j = 0; j < EPT; ++j) {
            int k = (int)(tv[j] * 512.0f);        // t in [0,2) by construction
            bkt[j] = k < NBUCK - 1 ? k : NBUCK - 1; // guard t rounding to 2.0
            rnk[j] = atomicAdd(&s_cnt[bkt[j]], 1);
        }
        __syncthreads();                                        // B1

        // ---- exclusive scan of counts -> packed (off<<12 | cnt) ----
        int4 cv = reinterpret_cast<int4*>(s_cnt)[tid];
        int c[EPT] = {cv.x, cv.y, cv.z, cv.w};
        int ls[EPT];
        int s = 0;
#pragma unroll
        for (int j = 0; j < EPT; ++j) { s += c[j]; ls[j] = s; }
        int x = wave_iscan_i32(s);
        if (lane == 63) s_isum[wid] = x;
        __syncthreads();                                        // B2
        int wbase = 0;
        for (int k2 = 0; k2 < wid; ++k2) wbase += s_isum[k2];
        int base = wbase + x - s; // exclusive prefix of this thread's first bucket
        int4 pv;
        pv.x = ((base + ls[0] - c[0]) << 12) | c[0];
        pv.y = ((base + ls[1] - c[1]) << 12) | c[1];
        pv.z = ((base + ls[2] - c[2]) << 12) | c[2];
        pv.w = ((base + ls[3] - c[3]) << 12) | c[3];
        reinterpret_cast<int4*>(s_cnt)[tid] = pv;
        __syncthreads();                                        // B3

        // ---- scatter (arrival order within bucket) ----
        int pc[EPT], pos[EPT];
#pragma unroll
        for (int j = 0; j < EPT; ++j) {
            pc[j]  = s_cnt[bkt[j]];
            pos[j] = (pc[j] >> 12) + rnk[j];
            s_tw[pos[j]] = make_float2(tv[j], wgt[j]);
        }
        __syncthreads();                                        // B4

        // ---- exact-rank fixup within multi-element buckets ----
        int npos[EPT];
#pragma unroll
        for (int j = 0; j < EPT; ++j) {
            npos[j] = -1;
            int cnt = pc[j] & 0xFFF;
            if (cnt > 1) {
                int bas = pc[j] >> 12;
                int r = 0;
                for (int k2 = bas; k2 < bas + cnt; ++k2) {
                    float tk = s_tw[k2].x;
                    r += (tk < tv[j]) || (tk == tv[j] && k2 < pos[j]);
                }
                npos[j] = bas + r;
            }
        }
        __syncthreads();                                        // B5
        // s_cnt is dead now: zero it for the next iteration (overlaps rewrite)
        reinterpret_cast<int4*>(s_cnt)[tid] = make_int4(0, 0, 0, 0);
#pragma unroll
        for (int j = 0; j < EPT; ++j) {
            if (npos[j] >= 0) s_tw[npos[j]] = make_float2(tv[j], wgt[j]);
        }
        __syncthreads();                                        // B6

        // ---- inclusive scan of (w, w*t) over sorted order ----
        float4 q0 = reinterpret_cast<const float4*>(s_tw)[tid * 2];
        float4 q1 = reinterpret_cast<const float4*>(s_tw)[tid * 2 + 1];
        float st[EPT] = {q0.x, q0.z, q1.x, q1.z};
        float sw[EPT] = {q0.y, q0.w, q1.y, q1.w};
        float cw[EPT], cwt[EPT];
        float aw = 0.f, awt = 0.f;
#pragma unroll
        for (int j = 0; j < EPT; ++j) { aw += sw[j]; awt += sw[j] * st[j]; cw[j] = aw; cwt[j] = awt; }
        float xw  = wave_iscan_f32(aw);
        float xwt = wave_iscan_f32(awt);
        if (lane == 63) { s_fw[wid] = xw; s_fwt[wid] = xwt; }
        float tnext = (tid < TPB - 1) ? s_tw[tid * EPT + EPT].x : 0.f;
        __syncthreads();                                        // B7
        float bw = 0.f, bwt = 0.f;
        for (int k2 = 0; k2 < wid; ++k2) { bw += s_fw[k2]; bwt += s_fwt[k2]; }
        bw += xw - aw; bwt += xwt - awt; // exclusive prefix for this thread

        // ---- candidates + min ----
        float m = INFINITY;
#pragma unroll
        for (int j = 0; j < EPT; ++j) {
            float W  = bw + cw[j];
            float WT = bwt + cwt[j];
            if (W > 0.f) {
                float tmp = (theta + WT) * __builtin_amdgcn_rcpf(W);
                bool ok = (tmp >= st[j]);          // !(tmp < t_k)
                int i = tid * EPT + j;
                if (i < PRE - 1) {
                    float tn = (j < EPT - 1) ? st[j + 1] : tnext;
                    ok = ok && (tmp <= tn);        // !(tmp > t_{k+1})
                }
                if (ok) m = fminf(m, tmp);
            }
        }
        m = fminf(m, __shfl_down(m, 32));
        m = fminf(m, __shfl_down(m, 16));
        m = dpp_min_f32<0x140>(m);  // row_mirror: i <-> 15-i
        m = dpp_min_f32<0x141>(m);  // half_mirror: i <-> 7-i
        m = dpp_min_f32<0x4E>(m);   // quad_perm [2,3,0,1]
        m = dpp_min_f32<0xB1>(m);   // quad_perm [1,0,3,2]
        if (lane == 0) s_red[wid] = m;
        __syncthreads();                                        // B8
        if (tid == 0) {
            out[b * POST + post] =
                fminf(fminf(s_red[0], s_red[1]), fminf(s_red[2], s_red[3]));
        }
    }
}

extern "C" void kernel_launch(void* const* d_in, const int* in_sizes, int n_in,
                              void* d_out, int out_size, void* d_ws, size_t ws_size,
                              hipStream_t stream) {
    const float* spikes     = (const float*)d_in[0]; // [32,1024]
    const float* weights    = (const float*)d_in[1]; // [1024,1024]
    const float* delays     = (const float*)d_in[2]; // [1024,1024]
    const float* thresholds = (const float*)d_in[3]; // [1024]
    float* outp = (float*)d_out;                     // [32,1024]

    dim3 grid(POST * (B_TOT / B_PER_WG)); // 4096 workgroups
    dim3 block(TPB);
    equaltime_kernel<<<grid, block, 0, stream>>>(spikes, weights, delays, thresholds, outp);
}